// Round 17
// baseline (52.865 us; speedup 1.0000x reference)
//
#include <hip/hip_runtime.h>
#include <hip/hip_bf16.h>

// ws layout (requires ws_size >= 17039360 B):
//   [0, 221184)        : weights as bf16 in 16x16x32 MFMA B-fragment order
//   [221184, 221440)   : 256 B of zeros (OOB halo source)
//   [262144, 17039360) : x_t = x transposed to [b][s][c] bf16 (16 MiB)
#define WS_W_OFF    0
#define WS_ZERO_OFF 221184
#define WS_XT_OFF   262144

typedef __attribute__((ext_vector_type(8))) short s16x8;
typedef __attribute__((ext_vector_type(4))) float f32x4;

#define GLOBAL_AS __attribute__((address_space(1)))
#define LDS_AS    __attribute__((address_space(3)))

__device__ __forceinline__ unsigned short f2bf(float f) {
  unsigned u = __builtin_bit_cast(unsigned, f);
  u = u + 0x7fffu + ((u >> 16) & 1u);
  return (unsigned short)(u >> 16);
}

// ---------------------------------------------------------------------------
// Fused prep (VERIFIED round 16, byte-identical). Blocks [0,432): weight
// repack. Blocks [432,944): x transpose via LDS tile, full-line stores.
__global__ void prep_kernel(const float* __restrict__ x,
                            const float* __restrict__ w,
                            unsigned short* __restrict__ wsw,
                            float* __restrict__ zeros,
                            unsigned short* __restrict__ xt) {
  int blk = blockIdx.x;
  int tid = threadIdx.x;
  if (blk < 432) {
    int t = blk * 256 + tid;                     // 110592 threads exactly
    int tap  = t % 27;
    int cin  = (t / 27) & 63;
    int cout = t / (27 * 64);
    int h   = cin >> 5;
    int q   = (cin >> 3) & 3;
    int j   = cin & 7;
    int nf  = cout >> 4;
    int lane = q * 16 + (cout & 15);
    int dst = (((tap * 2 + h) * 4 + nf) * 64 + lane) * 8 + j;
    wsw[dst] = f2bf(w[t]);
    if (t < 64) zeros[t] = 0.0f;
  } else {
    __shared__ __align__(16) unsigned char tile[256 * 144];  // 36864 B
    int bi = blk - 432;                          // 512 tiles
    int b  = bi >> 7;
    int s0 = (bi & 127) * 256;
    const float* xb = x + (size_t)b * 64 * 32768 + s0 + tid;
    #pragma unroll
    for (int c0 = 0; c0 < 64; c0 += 8) {
      s16x8 v;
      #pragma unroll
      for (int j = 0; j < 8; ++j)
        v[j] = (short)f2bf(xb[(size_t)(c0 + j) * 32768]);
      *(s16x8*)&tile[tid * 144 + c0 * 2] = v;
    }
    __syncthreads();
    #pragma unroll
    for (int it = 0; it < 8; ++it) {
      int row   = it * 32 + (tid >> 3);
      int col16 = tid & 7;
      s16x8 v = *(const s16x8*)&tile[row * 144 + col16 * 16];
      *(s16x8*)(xt + ((size_t)(b * 32768 + s0 + row) * 64 + col16 * 8)) = v;
    }
  }
}

// ---------------------------------------------------------------------------
// Implicit-GEMM conv with the m201-style PHASED schedule (T3+T4+T5):
// raw s_barrier pairs + COUNTED vmcnt (never drained mid-loop) + per-phase
// lgkmcnt(0) + setprio around the 16-MFMA cluster. This is the documented
// 8-phase mechanism (m218: counted-vs-drain = +38-73%) applied at conv's
// natural granularity (1 tap = 16 MFMA per phase).
//
// Geometry = VERIFIED R5/R9: block (b, z-pair, y-quad) = 2z x 4y x 32x = 256
// outputs x 64 couts, 4 waves, wave w: z = z0+(w>>1), y-rows {y0+2(w&1),+1}
// (M_w = 64). K = 64 as two cin-halves; halo per half 4z x 6y x 34x x 64 B =
// 52 KB; + B double-buffer 2 x 4 KB -> 61.4 KB LDS -> 2 blocks/CU.
//
// Phase t: stage_B(t+2) into the LDS buffer B(t) vacated at the previous
// barrier -> vmcnt(1) (waits stage(t+1) only; stage(t+2) stays in flight
// ACROSS the barriers) -> ds_read A(t+1),B(t+1) into parity regs ->
// s_barrier -> lgkmcnt(0)+sched_barrier(0) (rule #18) -> setprio(1),
// 16 MFMA(t), setprio(0) -> s_barrier.
//
// Halo LINEAR (pos p at halo[p*64], chunk c at +c*16; A-read = 8 dwords/bank
// = b128 floor). B LDS copy and read are both linear 16 B/lane.
__global__ __launch_bounds__(256, 2) void conv_kernel(const float* __restrict__ bias,
                                                      float* __restrict__ out,
                                                      const char* __restrict__ ws) {
  __shared__ __align__(16) unsigned char halo[52 * 1024];  // 832 pos (816 used)
  __shared__ __align__(16) unsigned char blds[2][4096];    // B tap dbuf

  const int tid  = threadIdx.x;
  const int lane = tid & 63;
  const int w    = tid >> 6;                     // wave id 0..3
  const int logical = (blockIdx.x & 7) * 64 + (blockIdx.x >> 3);
  const int yt = logical & 7, zt = (logical >> 3) & 15, b = logical >> 7;
  const int z0 = zt * 2, y0 = yt * 4;
  const int zo  = w >> 1;
  const int yo2 = (w & 1) * 2;

  const int r15 = lane & 15;
  const int hi4 = lane >> 4;

  const int sl_sub   = lane >> 2;
  const int sl_chunk = lane & 3;

  auto stage_halo = [&](int h) {
    for (int g = w; g < 52; g += 4) {            // 13 granules per wave
      int pos = g * 16 + sl_sub;
      int hz = pos / 204; int rem = pos - hz * 204;        // 204 = 6*34
      int hy = rem / 34;  int hx = rem - hy * 34;
      int gz = z0 + hz - 1, gy = y0 + hy - 1, gx = hx - 1;
      bool inb = (pos < 816) & ((unsigned)gz < 32u) &
                 ((unsigned)gy < 32u) & ((unsigned)gx < 32u);
      int s = (gz * 32 + gy) * 32 + gx;
      int src = inb ? (WS_XT_OFF + (b * 32768 + s) * 128 + h * 64 + sl_chunk * 16)
                    : WS_ZERO_OFF;
      __builtin_amdgcn_global_load_lds(
          (const GLOBAL_AS void*)(ws + src),
          (LDS_AS void*)(&halo[g * 1024 + lane * 16]),
          16, 0, 0);
    }
  };

  // one vmem instruction per wave: 256 threads x 16 B = one 4 KB tap tile
  auto stage_B = [&](int h, int tap, int buf) {
    __builtin_amdgcn_global_load_lds(
        (const GLOBAL_AS void*)(ws + WS_W_OFF + (tap * 2 + h) * 4096 + tid * 16),
        (LDS_AS void*)(&blds[buf][tid * 16]),
        16, 0, 0);
  };

  auto loadBlds = [&](s16x8* dst, int buf) {
    #pragma unroll
    for (int nf = 0; nf < 4; ++nf)
      dst[nf] = *(const s16x8*)&blds[buf][(nf * 64 + lane) * 16];
  };

  auto loadA = [&](s16x8* a, int tap) {
    int kd = tap / 9; int r9 = tap - kd * 9;
    int kh = r9 / 3;  int kw = r9 - kh * 3;      // folds under full unroll
    int base = ((zo + kd) * 6 + (yo2 + kh)) * 34 + kw + r15;
    #pragma unroll
    for (int mf = 0; mf < 4; ++mf) {
      int pos = base + (mf >> 1) * 34 + (mf & 1) * 16;
      a[mf] = *(const s16x8*)&halo[pos * 64 + hi4 * 16];
    }
  };

  f32x4 zero4 = {0.f, 0.f, 0.f, 0.f};
  f32x4 acc[4][4];
  #pragma unroll
  for (int mf = 0; mf < 4; ++mf)
    #pragma unroll
    for (int nf = 0; nf < 4; ++nf) acc[mf][nf] = zero4;

  s16x8 Ar[2][4], Br[2][4];                      // parity reg sets (static idx)

  auto compute = [&](const s16x8* a, const s16x8* B) {
    #pragma unroll
    for (int mf = 0; mf < 4; ++mf)
      #pragma unroll
      for (int nf = 0; nf < 4; ++nf)
        acc[mf][nf] = __builtin_amdgcn_mfma_f32_16x16x32_bf16(
            a[mf], B[nf], acc[mf][nf], 0, 0, 0);
  };

  auto run27 = [&](int h) {
    // prologue: B(0) in buf0 / B(1) in buf1 already staged & drained.
    loadBlds(Br[0], 0); loadA(Ar[0], 0);
    asm volatile("s_waitcnt lgkmcnt(0)");
    __builtin_amdgcn_s_barrier();      // B(0) regs live everywhere; buf0 free
    #pragma unroll
    for (int t = 0; t < 27; ++t) {
      const int cur = t & 1, nxt = cur ^ 1;
      if (t + 2 <= 26) {
        stage_B(h, t + 2, t & 1);      // overwrite B(t)'s buffer (vacated)
        asm volatile("s_waitcnt vmcnt(1)");   // stage(t+1) done; t+2 in flight
      } else if (t + 1 <= 26) {
        asm volatile("s_waitcnt vmcnt(0)");   // tail: only stage(26) left
      }
      if (t + 1 <= 26) {
        loadBlds(Br[nxt], (t + 1) & 1);
        loadA(Ar[nxt], t + 1);
      }
      __builtin_amdgcn_s_barrier();
      asm volatile("s_waitcnt lgkmcnt(0)");
      __builtin_amdgcn_sched_barrier(0);        // rule #18: pin MFMA after wait
      __builtin_amdgcn_s_setprio(1);
      compute(Ar[cur], Br[cur]);
      __builtin_amdgcn_s_setprio(0);
      __builtin_amdgcn_s_barrier();
    }
  };

  // ---- half 0 ----
  stage_halo(0);
  stage_B(0, 0, 0); stage_B(0, 1, 1);
  __syncthreads();                   // full drain: halo0 + B(0),B(1) ready
  run27(0);

  // ---- half 1 ----  (all halo-0 reads lgkmcnt-drained + barriered in run27)
  stage_halo(1);
  stage_B(1, 0, 0); stage_B(1, 1, 1);
  __syncthreads();                   // full drain: halo1 + B(0),B(1) ready
  run27(1);

  // ---- epilogue (verified 16x16 C/D): full-line coalesced stores ----
  const int z = z0 + zo;
  #pragma unroll
  for (int nf = 0; nf < 4; ++nf) {
    int cout = nf * 16 + r15;
    float bv = bias[cout];
    #pragma unroll
    for (int mf = 0; mf < 4; ++mf) {
      int y  = y0 + yo2 + (mf >> 1);
      int x0 = (mf & 1) * 16 + 4 * hi4;
      float* orow = out + ((size_t)((b * 64 + cout) * 32 + z) * 32 + y) * 32;
      f32x4 v;
      #pragma unroll
      for (int r = 0; r < 4; ++r) v[r] = acc[mf][nf][r] + bv;
      *(f32x4*)&orow[x0] = v;
    }
  }
}

extern "C" void kernel_launch(void* const* d_in, const int* in_sizes, int n_in,
                              void* d_out, int out_size, void* d_ws, size_t ws_size,
                              hipStream_t stream) {
  const float* x    = (const float*)d_in[0];
  const float* wgt  = (const float*)d_in[1];
  const float* bias = (const float*)d_in[2];
  float* out = (float*)d_out;
  char* ws = (char*)d_ws;

  prep_kernel<<<944, 256, 0, stream>>>(x, wgt,
                                       (unsigned short*)(ws + WS_W_OFF),
                                       (float*)(ws + WS_ZERO_OFF),
                                       (unsigned short*)(ws + WS_XT_OFF));
  conv_kernel<<<512, 256, 0, stream>>>(bias, out, ws);
}

// Round 18
// 44.911 us; speedup vs baseline: 1.1771x; 1.1771x over previous
//
#include <hip/hip_runtime.h>
#include <hip/hip_bf16.h>

// ws layout (requires ws_size >= 17039360 B):
//   [0, 221184)        : weights as bf16 in 16x16x32 MFMA B-fragment order
//   [221184, 221440)   : 256 B of zeros (OOB halo source)
//   [262144, 17039360) : x_t = x transposed to [b][s][c] bf16 (16 MiB)
#define WS_W_OFF    0
#define WS_ZERO_OFF 221184
#define WS_XT_OFF   262144

typedef __attribute__((ext_vector_type(8))) short s16x8;
typedef __attribute__((ext_vector_type(4))) float f32x4;

#define GLOBAL_AS __attribute__((address_space(1)))
#define LDS_AS    __attribute__((address_space(3)))

__device__ __forceinline__ unsigned short f2bf(float f) {
  unsigned u = __builtin_bit_cast(unsigned, f);
  u = u + 0x7fffu + ((u >> 16) & 1u);
  return (unsigned short)(u >> 16);
}

// ---------------------------------------------------------------------------
// Fused prep (VERIFIED round 16, byte-identical). Blocks [0,432): weight
// repack. Blocks [432,944): x transpose via LDS tile, full-line stores.
__global__ void prep_kernel(const float* __restrict__ x,
                            const float* __restrict__ w,
                            unsigned short* __restrict__ wsw,
                            float* __restrict__ zeros,
                            unsigned short* __restrict__ xt) {
  int blk = blockIdx.x;
  int tid = threadIdx.x;
  if (blk < 432) {
    int t = blk * 256 + tid;                     // 110592 threads exactly
    int tap  = t % 27;
    int cin  = (t / 27) & 63;
    int cout = t / (27 * 64);
    int h   = cin >> 5;
    int q   = (cin >> 3) & 3;
    int j   = cin & 7;
    int nf  = cout >> 4;
    int lane = q * 16 + (cout & 15);
    int dst = (((tap * 2 + h) * 4 + nf) * 64 + lane) * 8 + j;
    wsw[dst] = f2bf(w[t]);
    if (t < 64) zeros[t] = 0.0f;
  } else {
    __shared__ __align__(16) unsigned char tile[256 * 144];  // 36864 B
    int bi = blk - 432;                          // 512 tiles
    int b  = bi >> 7;
    int s0 = (bi & 127) * 256;
    const float* xb = x + (size_t)b * 64 * 32768 + s0 + tid;
    // phase 1: 8 cin-chunks; reads coalesced along s, LDS write conflict-free
    #pragma unroll
    for (int c0 = 0; c0 < 64; c0 += 8) {
      s16x8 v;
      #pragma unroll
      for (int j = 0; j < 8; ++j)
        v[j] = (short)f2bf(xb[(size_t)(c0 + j) * 32768]);
      *(s16x8*)&tile[tid * 144 + c0 * 2] = v;
    }
    __syncthreads();
    // phase 2: full-line stores, 1 KB contiguous per wave instruction
    #pragma unroll
    for (int it = 0; it < 8; ++it) {
      int row   = it * 32 + (tid >> 3);
      int col16 = tid & 7;
      s16x8 v = *(const s16x8*)&tile[row * 144 + col16 * 16];
      *(s16x8*)(xt + ((size_t)(b * 32768 + s0 + row) * 64 + col16 * 8)) = v;
    }
  }
}

// ---------------------------------------------------------------------------
// Implicit-GEMM conv (VERIFIED round 9/16, byte-identical): round-5 geometry
// + T4 counted-vmcnt register B pipeline.
// Block = (b, z-pair, y-quad): 2z x 4y x 32x = 256 outputs x 64 couts,
// 4 waves. Wave w: z = z0+(w>>1), y-rows {y0+2(w&1),+1}: M_w = 64.
// K = 64 as two cin-halves; halo per half: 4z x 6y x 34x pos x 64 B = 52 KB
// -> grid 512 = 2 blocks/CU (8 waves/CU).
// B: inline-asm global_load_dwordx4, 3-slot rotation, 2 taps ahead; per-tap
// s_waitcnt vmcnt(8/4/0) + sched_barrier(0x106). Halo LINEAR (pos p at
// halo[p*64], chunk c at +c*16; A-read = 8 dwords/bank = b128 floor).
__global__ __launch_bounds__(256, 2) void conv_kernel(const float* __restrict__ bias,
                                                      float* __restrict__ out,
                                                      const char* __restrict__ ws) {
  __shared__ __align__(16) unsigned char halo[52 * 1024];  // 832 pos (816 used)

  const int tid  = threadIdx.x;
  const int lane = tid & 63;
  const int w    = tid >> 6;                     // wave id 0..3
  const int logical = (blockIdx.x & 7) * 64 + (blockIdx.x >> 3);
  const int yt = logical & 7, zt = (logical >> 3) & 15, b = logical >> 7;
  const int z0 = zt * 2, y0 = yt * 4;
  const int zo  = w >> 1;
  const int yo2 = (w & 1) * 2;

  const int r15 = lane & 15;
  const int hi4 = lane >> 4;

  const int sl_sub   = lane >> 2;
  const int sl_chunk = lane & 3;

  auto stage_halo = [&](int h) {
    for (int g = w; g < 52; g += 4) {            // 13 granules per wave
      int pos = g * 16 + sl_sub;
      int hz = pos / 204; int rem = pos - hz * 204;        // 204 = 6*34
      int hy = rem / 34;  int hx = rem - hy * 34;
      int gz = z0 + hz - 1, gy = y0 + hy - 1, gx = hx - 1;
      bool inb = (pos < 816) & ((unsigned)gz < 32u) &
                 ((unsigned)gy < 32u) & ((unsigned)gx < 32u);
      int s = (gz * 32 + gy) * 32 + gx;
      int src = inb ? (WS_XT_OFF + (b * 32768 + s) * 128 + h * 64 + sl_chunk * 16)
                    : WS_ZERO_OFF;
      __builtin_amdgcn_global_load_lds(
          (const GLOBAL_AS void*)(ws + src),
          (LDS_AS void*)(&halo[g * 1024 + lane * 16]),
          16, 0, 0);
    }
  };

  const char* wsb_lane = ws + WS_W_OFF + lane * 16;

  f32x4 zero4 = {0.f, 0.f, 0.f, 0.f};
  f32x4 acc[4][4];
  #pragma unroll
  for (int mf = 0; mf < 4; ++mf)
    #pragma unroll
    for (int nf = 0; nf < 4; ++nf) acc[mf][nf] = zero4;

  s16x8 Bb[3][4];

  auto issueB = [&](int slot, int h, int tap) {
    const char* bt = wsb_lane + (tap * 2 + h) * 4096;
    asm volatile("global_load_dwordx4 %0, %1, off"             : "=v"(Bb[slot][0]) : "v"(bt));
    asm volatile("global_load_dwordx4 %0, %1, off offset:1024" : "=v"(Bb[slot][1]) : "v"(bt));
    asm volatile("global_load_dwordx4 %0, %1, off offset:2048" : "=v"(Bb[slot][2]) : "v"(bt));
    asm volatile("global_load_dwordx4 %0, %1, off offset:3072" : "=v"(Bb[slot][3]) : "v"(bt));
  };

  auto loadA = [&](s16x8* a, int tap) {
    int kd = tap / 9; int r9 = tap - kd * 9;
    int kh = r9 / 3;  int kw = r9 - kh * 3;      // folds under full unroll
    int base = ((zo + kd) * 6 + (yo2 + kh)) * 34 + kw + r15;
    #pragma unroll
    for (int mf = 0; mf < 4; ++mf) {
      int pos = base + (mf >> 1) * 34 + (mf & 1) * 16;
      a[mf] = *(const s16x8*)&halo[pos * 64 + hi4 * 16];
    }
  };

  auto compute = [&](const s16x8* a, const s16x8* B) {
    #pragma unroll
    for (int mf = 0; mf < 4; ++mf)
      #pragma unroll
      for (int nf = 0; nf < 4; ++nf)
        acc[mf][nf] = __builtin_amdgcn_mfma_f32_16x16x32_bf16(
            a[mf], B[nf], acc[mf][nf], 0, 0, 0);
  };

  auto run27 = [&](int h) {
    #pragma unroll
    for (int tap = 0; tap < 27; ++tap) {
      if (tap < 25) issueB((tap + 2) % 3, h, tap + 2);     // static slot
      if (tap < 25)        { asm volatile("s_waitcnt vmcnt(8)"); }
      else if (tap == 25)  { asm volatile("s_waitcnt vmcnt(4)"); }
      else                 { asm volatile("s_waitcnt vmcnt(0)"); }
      __builtin_amdgcn_sched_barrier(0x106);   // DS_READ|VALU|SALU may cross
      s16x8 Af[4];
      loadA(Af, tap);
      compute(Af, Bb[tap % 3]);
    }
  };

  stage_halo(0);
  issueB(0, 0, 0); issueB(1, 0, 1);  // overlaps halo staging latency
  __syncthreads();                   // drains vmcnt; halo 0 + B(0,1) ready
  run27(0);

  issueB(0, 1, 0); issueB(1, 1, 1);  // half-1 B prologue (doesn't touch halo)
  __syncthreads();                   // all waves done reading half-0 halo
  stage_halo(1);
  __syncthreads();                   // halo 1 ready (drains everything)
  run27(1);

  const int z = z0 + zo;
  #pragma unroll
  for (int nf = 0; nf < 4; ++nf) {
    int cout = nf * 16 + r15;
    float bv = bias[cout];
    #pragma unroll
    for (int mf = 0; mf < 4; ++mf) {
      int y  = y0 + yo2 + (mf >> 1);
      int x0 = (mf & 1) * 16 + 4 * hi4;
      float* orow = out + ((size_t)((b * 64 + cout) * 32 + z) * 32 + y) * 32;
      f32x4 v;
      #pragma unroll
      for (int r = 0; r < 4; ++r) v[r] = acc[mf][nf][r] + bv;
      *(f32x4*)&orow[x0] = v;
    }
  }
}

extern "C" void kernel_launch(void* const* d_in, const int* in_sizes, int n_in,
                              void* d_out, int out_size, void* d_ws, size_t ws_size,
                              hipStream_t stream) {
  const float* x    = (const float*)d_in[0];
  const float* wgt  = (const float*)d_in[1];
  const float* bias = (const float*)d_in[2];
  float* out = (float*)d_out;
  char* ws = (char*)d_ws;

  prep_kernel<<<944, 256, 0, stream>>>(x, wgt,
                                       (unsigned short*)(ws + WS_W_OFF),
                                       (float*)(ws + WS_ZERO_OFF),
                                       (unsigned short*)(ws + WS_XT_OFF));
  conv_kernel<<<512, 256, 0, stream>>>(bias, out, ws);
}